// Round 3
// baseline (448.586 us; speedup 1.0000x reference)
//
#include <hip/hip_runtime.h>
#include <math.h>

#define N_NODES 50000
#define N_EDGES 800000
#define DIM_IN 64
#define DIM_HID 128
#define DIM_OUT 64
#define PAD 136   // bf16 per weight row: 272B, 16B-aligned

typedef __attribute__((ext_vector_type(8))) short short8;   // 8 bf16 (4 VGPRs)
typedef __attribute__((ext_vector_type(4))) float f32x4;    // MFMA accumulator

union U8 { uint4 u; short8 s; };

// RTNE float->bf16 (inputs finite) -- software path, used only in weight prep
__device__ __forceinline__ unsigned short f2bf(float f) {
    unsigned u = __float_as_uint(f);
    return (unsigned short)((u + 0x7fffu + ((u >> 16) & 1u)) >> 16);
}

// gfx950 has NO cvt_pk_bf16 builtin (learn_hip m240). Single VOP3 via asm.
// lo = a, hi = b; RTNE (default round mode) == the software f2bf path.
__device__ __forceinline__ unsigned cvt_pk_bf16(float a, float b) {
    unsigned d;
    asm("v_cvt_pk_bf16_f32 %0, %1, %2" : "=v"(d) : "v"(a), "v"(b));
    return d;
}

__device__ __forceinline__ float exp2_fast(float a) {
#if __has_builtin(__builtin_amdgcn_exp2f)
    return __builtin_amdgcn_exp2f(a);
#else
    return __expf(a * 0.69314718f);
#endif
}

// softplus(x) = max(x,0) + log1p(exp(-|x|)); log1p(z) ~ z*(1 + z*(-0.5 + z*(A + z*B)))
// cubic fit on z in (0,1], max abs err ~1.5e-3 (below bf16 quantization of H)
__device__ __forceinline__ unsigned sp2(float x0, float x1) {
    const float L2E = 1.44269504f;
    float z0 = exp2_fast(-fabsf(x0) * L2E);
    float z1 = exp2_fast(-fabsf(x1) * L2E);
    float p0 = fmaf(fmaf(fmaf(-0.1011458f, z0, 0.2942925f), z0, -0.5f), z0, 1.0f) * z0;
    float p1 = fmaf(fmaf(fmaf(-0.1011458f, z1, 0.2942925f), z1, -0.5f), z1, 1.0f) * z1;
    return cvt_pk_bf16(fmaxf(x0, 0.0f) + p0, fmaxf(x1, 0.0f) + p1);
}

// Fused prep: zero output accumulator + histogram, convert x to bf16 table,
// build bf16 W^T [n][PAD] tables (layers 1,2 carry the K-permutation pi).
__global__ void prep_all(const float* __restrict__ x,
                         const float* __restrict__ W0,
                         const float* __restrict__ W1,
                         const float* __restrict__ W2,
                         unsigned short* __restrict__ wt,
                         unsigned short* __restrict__ xbf,
                         float4* __restrict__ outz,
                         int* __restrict__ hist) {
    int i = blockIdx.x * blockDim.x + threadIdx.x;

    if (i < (N_NODES * DIM_OUT / 4))                 // 800000 float4 = 12.8 MB
        outz[i] = make_float4(0.f, 0.f, 0.f, 0.f);

    if (i < (N_NODES * DIM_IN / 4)) {                // 800000 float4 -> uint2 bf16
        float4 v = *((const float4*)x + i);
        uint2 p;
        p.x = cvt_pk_bf16(v.x, v.y);
        p.y = cvt_pk_bf16(v.z, v.w);
        *((uint2*)xbf + i) = p;
    }

    if (hist && i < N_NODES) hist[i] = 0;

    if (i < 320 * PAD) {                             // 43520 weight elements
        int row = i / PAD, s = i - row * PAD;
        float v = 0.f;
        if (s < 128) {
            int f = ((s >> 5) << 5) | (((s & 7) >> 2) << 4) | (((s >> 3) & 3) << 2) | (s & 3);
            if (row < 128)      v = W0[s * DIM_HID + row];          // layer 0: natural k
            else if (row < 256) v = W1[f * DIM_HID + (row - 128)];  // layer 1: permuted k
            else                v = W2[f * DIM_OUT + (row - 256)];  // layer 2: permuted k
        }
        wt[i] = f2bf(v);
    }
}

// ---- counting-sort passes (edges by destination row) ----
__global__ void hist_kernel(const int* __restrict__ eidx, int* __restrict__ hist) {
    int i = blockIdx.x * blockDim.x + threadIdx.x;
    if (i < N_EDGES) atomicAdd(&hist[eidx[i]], 1);
}

// single-block exclusive scan of 50000 bins -> cursor[]
__global__ __launch_bounds__(1024)
void scan_bins(const int* __restrict__ hist, int* __restrict__ cursor) {
    __shared__ int part[1024];
    const int t = threadIdx.x;
    const int CH = (N_NODES + 1023) / 1024;          // 49
    const int base = t * CH;
    int s = 0;
    for (int j = 0; j < CH; ++j) {
        int b = base + j;
        if (b < N_NODES) s += hist[b];
    }
    part[t] = s;
    __syncthreads();
    for (int off = 1; off < 1024; off <<= 1) {       // Hillis-Steele inclusive
        int u = (t >= off) ? part[t - off] : 0;
        __syncthreads();
        part[t] += u;
        __syncthreads();
    }
    int run = (t == 0) ? 0 : part[t - 1];            // exclusive
    for (int j = 0; j < CH; ++j) {
        int b = base + j;
        if (b < N_NODES) { cursor[b] = run; run += hist[b]; }
    }
}

__global__ void scatter_kernel(const int* __restrict__ eidx,
                               int* __restrict__ cursor,
                               int* __restrict__ srow,
                               int* __restrict__ scol) {
    int i = blockIdx.x * blockDim.x + threadIdx.x;
    if (i >= N_EDGES) return;
    int r = eidx[i];
    int c = eidx[N_EDGES + i];
    int pos = atomicAdd(&cursor[r], 1);
    srow[pos] = r;
    scol[pos] = c;
}

// Layers 0,1 flipped: H^T = softplus(W^T H^T + b) via mfma(A=weight, B=activation).
// Layer 2 un-flipped: O = H W2 + b2 via mfma(A=activation, B=weight); C row=edge.
//
// MODE 0: f32 x-gather, unsorted edges (legacy fallback).
// MODE 1: bf16 x-table gather, unsorted edges.
// MODE 2: bf16 x-table gather, SORTED edges + in-register segmented emission:
//   a lane's quad owns 8 sorted-consecutive edges (m*16+q*4+r); node ids are
//   non-decreasing across the 8, so same-node outputs merge in registers and
//   one atomic burst per run is emitted. Random edges avg degree 16 -> ~1.4
//   runs per 8-edge window -> ~5.5x fewer lane-atomics (the measured binder:
//   WRITE_SIZE == 4B * lane-atomics, ~241 G atomics/s rate floor).
template <int MODE>
__global__ __launch_bounds__(256, 4)
void edge_mlp_mfma(const float* __restrict__ x,
                   const unsigned short* __restrict__ xbf,
                   const int* __restrict__ srow,
                   const int* __restrict__ scol,
                   const int* __restrict__ eidx,
                   const unsigned short* __restrict__ wt,
                   const float* __restrict__ b0,
                   const float* __restrict__ b1,
                   const float* __restrict__ b2,
                   float* __restrict__ out) {
    const int lane = threadIdx.x & 63;
    const int w    = threadIdx.x >> 6;
    const int l16  = lane & 15;
    const int q    = lane >> 4;
    const int e0w  = blockIdx.x * 128 + w * 32;   // this wave's 32 edges

    const unsigned short* Wt0 = wt;
    const unsigned short* Wt1 = wt + 128 * PAD;
    const unsigned short* Wt2 = wt + 256 * PAD;

    int nodeR[2], nodeC[2];
#pragma unroll
    for (int m = 0; m < 2; ++m) {
        if (MODE == 2) {
            nodeR[m] = srow[e0w + m * 16 + l16];   // sorted: L1-broadcast friendly
            nodeC[m] = scol[e0w + m * 16 + l16];
        } else {
            nodeR[m] = eidx[e0w + m * 16 + l16];
            nodeC[m] = eidx[N_EDGES + e0w + m * 16 + l16];
        }
    }

    // layer-2 scatter nodes for this quad's 8 edges, loaded before compute
    int ns[8];
#pragma unroll
    for (int m = 0; m < 2; ++m)
#pragma unroll
        for (int r = 0; r < 4; ++r)
            ns[m * 4 + r] = (MODE == 2) ? srow[e0w + m * 16 + q * 4 + r]
                                        : eidx[e0w + m * 16 + q * 4 + r];

    // layer-0 B-frags: B(k=kk*32+q*8+j, edge=m*16+l16)
    short8 hfr[2][4];
#pragma unroll
    for (int m = 0; m < 2; ++m)
#pragma unroll
        for (int kk = 0; kk < 4; ++kk) {
            int node = (kk >= 2) ? nodeC[m] : nodeR[m];
            if (MODE >= 1) {
                hfr[m][kk] = *(const short8*)(xbf + (size_t)node * DIM_IN + (kk & 1) * 32 + q * 8);
            } else {
                const float* p = x + (size_t)node * DIM_IN + (kk & 1) * 32 + q * 8;
                float4 v0 = *(const float4*)p;
                float4 v1 = *(const float4*)(p + 4);
                U8 t;
                t.u.x = cvt_pk_bf16(v0.x, v0.y);
                t.u.y = cvt_pk_bf16(v0.z, v0.w);
                t.u.z = cvt_pk_bf16(v1.x, v1.y);
                t.u.w = cvt_pk_bf16(v1.z, v1.w);
                hfr[m][kk] = t.s;
            }
        }

    // ---- layers 0,1: H^T = softplus(W^T H^T + b) (simple per-ti form) ----
#pragma unroll
    for (int L = 0; L < 2; ++L) {
        const unsigned short* W = L ? Wt1 : Wt0;
        const float* bias = L ? b1 : b0;
        unsigned d[2][8][2];
#pragma unroll
        for (int ti = 0; ti < 8; ++ti) {
            f32x4 bb = *(const f32x4*)(bias + ti * 16 + q * 4);  // bias on row dim
            f32x4 a0 = bb, a1 = bb;
            const unsigned short* Wp = W + (ti * 16 + l16) * PAD + q * 8;
            short8 wf[4];
#pragma unroll
            for (int kk = 0; kk < 4; ++kk)
                wf[kk] = *(const short8*)(Wp + kk * 32);
#pragma unroll
            for (int kk = 0; kk < 4; ++kk) {
                a0 = __builtin_amdgcn_mfma_f32_16x16x32_bf16(wf[kk], hfr[0][kk], a0, 0, 0, 0);
                a1 = __builtin_amdgcn_mfma_f32_16x16x32_bf16(wf[kk], hfr[1][kk], a1, 0, 0, 0);
            }
            // per-ti epilogue keeps acc liveness at 8 VGPRs
            d[0][ti][0] = sp2(a0[0], a0[1]);
            d[0][ti][1] = sp2(a0[2], a0[3]);
            d[1][ti][0] = sp2(a1[0], a1[1]);
            d[1][ti][1] = sp2(a1[2], a1[3]);
        }
        // next-layer frags: pure register renaming (weights carry pi)
#pragma unroll
        for (int m = 0; m < 2; ++m)
#pragma unroll
            for (int kk = 0; kk < 4; ++kk) {
                U8 t;
                t.u.x = d[m][2 * kk][0];
                t.u.y = d[m][2 * kk][1];
                t.u.z = d[m][2 * kk + 1][0];
                t.u.w = d[m][2 * kk + 1][1];
                hfr[m][kk] = t.s;
            }
    }

    // ---- layer 2 (un-flipped): O = H W2 + b2; C row=edge, col=feature ----
    // All loads complete before any atomic issues (vmcnt is in-order).
    {
        f32x4 acc[4][2];
#pragma unroll
        for (int ti = 0; ti < 4; ++ti) {
            float bv = b2[ti * 16 + l16];                    // bias on col dim
            f32x4 a0 = (f32x4){bv, bv, bv, bv};
            f32x4 a1 = a0;
            const unsigned short* Wp = Wt2 + (ti * 16 + l16) * PAD + q * 8;
            short8 wf[4];
#pragma unroll
            for (int kk = 0; kk < 4; ++kk)
                wf[kk] = *(const short8*)(Wp + kk * 32);
#pragma unroll
            for (int kk = 0; kk < 4; ++kk) {
                a0 = __builtin_amdgcn_mfma_f32_16x16x32_bf16(hfr[0][kk], wf[kk], a0, 0, 0, 0);
                a1 = __builtin_amdgcn_mfma_f32_16x16x32_bf16(hfr[1][kk], wf[kk], a1, 0, 0, 0);
            }
            acc[ti][0] = a0;
            acc[ti][1] = a1;
        }

        if (MODE == 2) {
            // segmented emission: merge same-node rows in registers first.
            // ns[0..7] is non-decreasing (sorted edges); quad-uniform values.
            int curn = ns[0];
            float c0 = 0.f, c1 = 0.f, c2 = 0.f, c3 = 0.f;
#pragma unroll
            for (int s = 0; s < 8; ++s) {
                const int m = s >> 2, r = s & 3;
                if (s > 0 && ns[s] != curn) {
                    float* o = out + (size_t)curn * DIM_OUT + l16;
                    atomicAdd(o +  0, c0);
                    atomicAdd(o + 16, c1);
                    atomicAdd(o + 32, c2);
                    atomicAdd(o + 48, c3);
                    c0 = c1 = c2 = c3 = 0.f;
                    curn = ns[s];
                }
                c0 += acc[0][m][r];
                c1 += acc[1][m][r];
                c2 += acc[2][m][r];
                c3 += acc[3][m][r];
            }
            float* o = out + (size_t)curn * DIM_OUT + l16;
            atomicAdd(o +  0, c0);
            atomicAdd(o + 16, c1);
            atomicAdd(o + 32, c2);
            atomicAdd(o + 48, c3);
        } else {
#pragma unroll
            for (int ti = 0; ti < 4; ++ti)
#pragma unroll
                for (int r = 0; r < 4; ++r) {
                    atomicAdd(out + (size_t)ns[r] * DIM_OUT + ti * 16 + l16, acc[ti][0][r]);
                    atomicAdd(out + (size_t)ns[4 + r] * DIM_OUT + ti * 16 + l16, acc[ti][1][r]);
                }
        }
    }
}

extern "C" void kernel_launch(void* const* d_in, const int* in_sizes, int n_in,
                              void* d_out, int out_size, void* d_ws, size_t ws_size,
                              hipStream_t stream) {
    const float* x  = (const float*)d_in[0];
    const int*   ei = (const int*)d_in[1];
    const float* W0 = (const float*)d_in[2];
    const float* b0 = (const float*)d_in[3];
    const float* W1 = (const float*)d_in[4];
    const float* b1 = (const float*)d_in[5];
    const float* W2 = (const float*)d_in[6];
    const float* b2 = (const float*)d_in[7];
    float* out = (float*)d_out;

    char* ws = (char*)d_ws;
    const size_t WT_BYTES   = (size_t)320 * PAD * 2;            // 87040
    const size_t XBF_BYTES  = (size_t)N_NODES * DIM_IN * 2;     // 6400000
    const size_t HIST_BYTES = 200192;                            // 50000*4 padded
    const size_t SROW_BYTES = (size_t)N_EDGES * 4;               // 3200000

    unsigned short* wt  = (unsigned short*)ws;
    unsigned short* xbf = (unsigned short*)(ws + WT_BYTES);
    int* hist   = (int*)(ws + WT_BYTES + XBF_BYTES);
    int* cursor = (int*)(ws + WT_BYTES + XBF_BYTES + HIST_BYTES);
    int* srow   = (int*)(ws + WT_BYTES + XBF_BYTES + 2 * HIST_BYTES);
    int* scol   = (int*)(ws + WT_BYTES + XBF_BYTES + 2 * HIST_BYTES + SROW_BYTES);

    const size_t need_sorted = WT_BYTES + XBF_BYTES + 2 * HIST_BYTES + 2 * SROW_BYTES; // ~13.3 MB
    const size_t need_xbf    = WT_BYTES + XBF_BYTES;                                    // ~6.5 MB

    if (ws_size >= need_sorted) {
        prep_all<<<(N_NODES * DIM_IN / 4 + 255) / 256, 256, 0, stream>>>(
            x, W0, W1, W2, wt, xbf, (float4*)out, hist);
        hist_kernel<<<(N_EDGES + 255) / 256, 256, 0, stream>>>(ei, hist);
        scan_bins<<<1, 1024, 0, stream>>>(hist, cursor);
        scatter_kernel<<<(N_EDGES + 255) / 256, 256, 0, stream>>>(ei, cursor, srow, scol);
        edge_mlp_mfma<2><<<N_EDGES / 128, 256, 0, stream>>>(
            x, xbf, srow, scol, ei, wt, b0, b1, b2, out);
    } else if (ws_size >= need_xbf) {
        prep_all<<<(N_NODES * DIM_IN / 4 + 255) / 256, 256, 0, stream>>>(
            x, W0, W1, W2, wt, xbf, (float4*)out, nullptr);
        edge_mlp_mfma<1><<<N_EDGES / 128, 256, 0, stream>>>(
            x, xbf, nullptr, nullptr, ei, wt, b0, b1, b2, out);
    } else {
        hipMemsetAsync(out, 0, (size_t)N_NODES * DIM_OUT * sizeof(float), stream);
        prep_all<<<(N_NODES * DIM_IN / 4 + 255) / 256, 256, 0, stream>>>(
            x, W0, W1, W2, wt, (unsigned short*)wt, (float4*)out, nullptr);  // wt only (xbf aliased, unused)
        edge_mlp_mfma<0><<<N_EDGES / 128, 256, 0, stream>>>(
            x, nullptr, nullptr, nullptr, ei, wt, b0, b1, b2, out);
    }
}

// Round 4
// 266.683 us; speedup vs baseline: 1.6821x; 1.6821x over previous
//
#include <hip/hip_runtime.h>
#include <math.h>

#define N_NODES 50000
#define N_EDGES 800000
#define DIM_IN 64
#define DIM_HID 128
#define DIM_OUT 64
#define PAD 136   // bf16 per weight row: 272B, 16B-aligned

typedef __attribute__((ext_vector_type(8))) short short8;   // 8 bf16 (4 VGPRs)
typedef __attribute__((ext_vector_type(4))) float f32x4;    // MFMA accumulator

union U8 { uint4 u; short8 s; };

// RTNE float->bf16 (inputs finite) -- software path, used only in weight prep
__device__ __forceinline__ unsigned short f2bf(float f) {
    unsigned u = __float_as_uint(f);
    return (unsigned short)((u + 0x7fffu + ((u >> 16) & 1u)) >> 16);
}

// gfx950 has NO cvt_pk_bf16 builtin (learn_hip m240). Single VOP3 via asm.
// lo = a, hi = b; RTNE (default round mode) == the software f2bf path.
__device__ __forceinline__ unsigned cvt_pk_bf16(float a, float b) {
    unsigned d;
    asm("v_cvt_pk_bf16_f32 %0, %1, %2" : "=v"(d) : "v"(a), "v"(b));
    return d;
}

__device__ __forceinline__ float exp2_fast(float a) {
#if __has_builtin(__builtin_amdgcn_exp2f)
    return __builtin_amdgcn_exp2f(a);
#else
    return __expf(a * 0.69314718f);
#endif
}

// softplus(x) = max(x,0) + log1p(exp(-|x|)); log1p(z) ~ z*(1 + z*(-0.5 + z*(A + z*B)))
// cubic fit on z in (0,1], max abs err ~1.5e-3 (below bf16 quantization of H)
__device__ __forceinline__ unsigned sp2(float x0, float x1) {
    const float L2E = 1.44269504f;
    float z0 = exp2_fast(-fabsf(x0) * L2E);
    float z1 = exp2_fast(-fabsf(x1) * L2E);
    float p0 = fmaf(fmaf(fmaf(-0.1011458f, z0, 0.2942925f), z0, -0.5f), z0, 1.0f) * z0;
    float p1 = fmaf(fmaf(fmaf(-0.1011458f, z1, 0.2942925f), z1, -0.5f), z1, 1.0f) * z1;
    return cvt_pk_bf16(fmaxf(x0, 0.0f) + p0, fmaxf(x1, 0.0f) + p1);
}

// Fused prep: zero the output accumulator, convert x to a bf16 table, and
// build the bf16 W^T [n][PAD] tables (layers 1,2 carry the K-permutation pi
// matching the MFMA C-layout -> frag register renaming; see main kernel).
__global__ void prep_all(const float* __restrict__ x,
                         const float* __restrict__ W0,
                         const float* __restrict__ W1,
                         const float* __restrict__ W2,
                         unsigned short* __restrict__ wt,
                         unsigned short* __restrict__ xbf,
                         float4* __restrict__ outz) {
    int i = blockIdx.x * blockDim.x + threadIdx.x;

    if (i < (N_NODES * DIM_OUT / 4))                 // 800000 float4 = 12.8 MB
        outz[i] = make_float4(0.f, 0.f, 0.f, 0.f);

    if (i < (N_NODES * DIM_IN / 4)) {                // 800000 float4 -> uint2 bf16
        float4 v = *((const float4*)x + i);
        uint2 p;
        p.x = cvt_pk_bf16(v.x, v.y);
        p.y = cvt_pk_bf16(v.z, v.w);
        *((uint2*)xbf + i) = p;
    }

    if (i < 320 * PAD) {                             // 43520 weight elements
        int row = i / PAD, s = i - row * PAD;
        float v = 0.f;
        if (s < 128) {
            int f = ((s >> 5) << 5) | (((s & 7) >> 2) << 4) | (((s >> 3) & 3) << 2) | (s & 3);
            if (row < 128)      v = W0[s * DIM_HID + row];          // layer 0: natural k
            else if (row < 256) v = W1[f * DIM_HID + (row - 128)];  // layer 1: permuted k
            else                v = W2[f * DIM_OUT + (row - 256)];  // layer 2: permuted k
        }
        wt[i] = f2bf(v);
    }
}

// Weights-only prep for the fallback (workspace too small for the x table).
__global__ void prep_weights(const float* __restrict__ W0,
                             const float* __restrict__ W1,
                             const float* __restrict__ W2,
                             unsigned short* __restrict__ wt) {
    int i = blockIdx.x * blockDim.x + threadIdx.x;
    if (i >= 320 * PAD) return;
    int row = i / PAD, s = i - row * PAD;
    float v = 0.f;
    if (s < 128) {
        int f = ((s >> 5) << 5) | (((s & 7) >> 2) << 4) | (((s >> 3) & 3) << 2) | (s & 3);
        if (row < 128)      v = W0[s * DIM_HID + row];
        else if (row < 256) v = W1[f * DIM_HID + (row - 128)];
        else                v = W2[f * DIM_OUT + (row - 256)];
    }
    wt[i] = f2bf(v);
}

// Layers 0,1 flipped: H^T = softplus(W^T H^T + b) via mfma(A=weight, B=activation).
// Layer 2 un-flipped: O = H W2 + b2 via mfma(A=activation, B=weight); C row=edge.
//
// THIS ROUND: weights staged in LDS per layer. Previously every wave privately
// streamed the whole 87KB weight table through a thrashed 32KB L1 (the measured
// invariant binder: dur pinned ~205us across fetch/atomic diets). Now each
// BLOCK loads each layer's table once (coalesced, 2176/1088 uint4), computes
// from ds_read_b128 (lgkmcnt path, decoupled from the gather/atomic vmcnt
// queue; row stride 272B rotates start banks by 4 -> 8 dwords/bank/instr =
// width-limited, no conflict penalty). LDS 34,816B/block -> 4 blocks/CU.
template <bool XB>
__global__ __launch_bounds__(256, 4)
void edge_mlp_mfma(const float* __restrict__ x,
                   const unsigned short* __restrict__ xbf,
                   const int* __restrict__ eidx,
                   const unsigned short* __restrict__ wt,
                   const float* __restrict__ b0,
                   const float* __restrict__ b1,
                   const float* __restrict__ b2,
                   float* __restrict__ out) {
    __shared__ unsigned short lw[128 * PAD];   // 34,816 B: one layer's W^T table

    const int lane = threadIdx.x & 63;
    const int w    = threadIdx.x >> 6;
    const int l16  = lane & 15;
    const int q    = lane >> 4;
    const int e0w  = blockIdx.x * 128 + w * 32;   // this wave's 32 edges

    int nodeR[2], nodeC[2];
#pragma unroll
    for (int m = 0; m < 2; ++m) {
        nodeR[m] = eidx[e0w + m * 16 + l16];
        nodeC[m] = eidx[N_EDGES + e0w + m * 16 + l16];
    }

    // layer-2 scatter nodes for this quad's 8 edges (L1-hot reload)
    int ns[8];
#pragma unroll
    for (int m = 0; m < 2; ++m)
#pragma unroll
        for (int r = 0; r < 4; ++r)
            ns[m * 4 + r] = eidx[e0w + m * 16 + q * 4 + r];

    // layer-0 B-frags: B(k=kk*32+q*8+j, edge=m*16+l16)  (HBM/L2 gather; issued
    // early so its latency hides under the L0 staging + barrier)
    short8 hfr[2][4];
#pragma unroll
    for (int m = 0; m < 2; ++m)
#pragma unroll
        for (int kk = 0; kk < 4; ++kk) {
            int node = (kk >= 2) ? nodeC[m] : nodeR[m];
            if (XB) {
                hfr[m][kk] = *(const short8*)(xbf + (size_t)node * DIM_IN + (kk & 1) * 32 + q * 8);
            } else {
                const float* p = x + (size_t)node * DIM_IN + (kk & 1) * 32 + q * 8;
                float4 v0 = *(const float4*)p;
                float4 v1 = *(const float4*)(p + 4);
                U8 t;
                t.u.x = cvt_pk_bf16(v0.x, v0.y);
                t.u.y = cvt_pk_bf16(v0.z, v0.w);
                t.u.z = cvt_pk_bf16(v1.x, v1.y);
                t.u.w = cvt_pk_bf16(v1.z, v1.w);
                hfr[m][kk] = t.s;
            }
        }

    // stage layer-0 weights: rows 0..127, 2176 uint4, coalesced
    {
        const uint4* src = (const uint4*)wt;
        uint4* dst = (uint4*)lw;
        for (int i = threadIdx.x; i < 2176; i += 256) dst[i] = src[i];
    }
    __syncthreads();

    // ---- layers 0,1: H^T = softplus(W^T H^T + b), weights from LDS ----
#pragma unroll
    for (int L = 0; L < 2; ++L) {
        const float* bias = L ? b1 : b0;
        unsigned d[2][8][2];
#pragma unroll
        for (int ti = 0; ti < 8; ++ti) {
            f32x4 bb = *(const f32x4*)(bias + ti * 16 + q * 4);  // bias on row dim
            f32x4 a0 = bb, a1 = bb;
            const unsigned short* Wp = lw + (ti * 16 + l16) * PAD + q * 8;
            short8 wf[4];
#pragma unroll
            for (int kk = 0; kk < 4; ++kk)
                wf[kk] = *(const short8*)(Wp + kk * 32);         // ds_read_b128
#pragma unroll
            for (int kk = 0; kk < 4; ++kk) {
                a0 = __builtin_amdgcn_mfma_f32_16x16x32_bf16(wf[kk], hfr[0][kk], a0, 0, 0, 0);
                a1 = __builtin_amdgcn_mfma_f32_16x16x32_bf16(wf[kk], hfr[1][kk], a1, 0, 0, 0);
            }
            // per-ti epilogue keeps acc liveness at 8 VGPRs
            d[0][ti][0] = sp2(a0[0], a0[1]);
            d[0][ti][1] = sp2(a0[2], a0[3]);
            d[1][ti][0] = sp2(a1[0], a1[1]);
            d[1][ti][1] = sp2(a1[2], a1[3]);
        }
        // next-layer frags: pure register renaming (weights carry pi)
#pragma unroll
        for (int m = 0; m < 2; ++m)
#pragma unroll
            for (int kk = 0; kk < 4; ++kk) {
                U8 t;
                t.u.x = d[m][2 * kk][0];
                t.u.y = d[m][2 * kk][1];
                t.u.z = d[m][2 * kk + 1][0];
                t.u.w = d[m][2 * kk + 1][1];
                hfr[m][kk] = t.s;
            }
        // stage next layer's weights (L=0: rows 128..255; L=1: rows 256..319)
        __syncthreads();   // all waves done reading current table
        {
            const uint4* src = (const uint4*)(wt + (size_t)(L ? 256 : 128) * PAD);
            uint4* dst = (uint4*)lw;
            const int n = L ? 1088 : 2176;
            for (int i = threadIdx.x; i < n; i += 256) dst[i] = src[i];
        }
        __syncthreads();
    }

    // ---- layer 2 (un-flipped): O = H W2 + b2; C row=edge, col=feature ----
    // All loads complete before any atomic issues (vmcnt is in-order).
    {
        f32x4 acc[4][2];
#pragma unroll
        for (int ti = 0; ti < 4; ++ti) {
            float bv = b2[ti * 16 + l16];                    // bias on col dim
            f32x4 a0 = (f32x4){bv, bv, bv, bv};
            f32x4 a1 = a0;
            const unsigned short* Wp = lw + (ti * 16 + l16) * PAD + q * 8;
            short8 wf[4];
#pragma unroll
            for (int kk = 0; kk < 4; ++kk)
                wf[kk] = *(const short8*)(Wp + kk * 32);      // ds_read_b128
#pragma unroll
            for (int kk = 0; kk < 4; ++kk) {
                a0 = __builtin_amdgcn_mfma_f32_16x16x32_bf16(hfr[0][kk], wf[kk], a0, 0, 0, 0);
                a1 = __builtin_amdgcn_mfma_f32_16x16x32_bf16(hfr[1][kk], wf[kk], a1, 0, 0, 0);
            }
            acc[ti][0] = a0;
            acc[ti][1] = a1;
        }

        // terminal atomic burst: fire-and-forget, nothing waits on the acks.
        // each instruction covers full 64B sectors (quad-uniform node, l16 lanes
        // contiguous), 4 transactions/instr.
#pragma unroll
        for (int ti = 0; ti < 4; ++ti)
#pragma unroll
            for (int r = 0; r < 4; ++r) {
                atomicAdd(out + (size_t)ns[r] * DIM_OUT + ti * 16 + l16, acc[ti][0][r]);
                atomicAdd(out + (size_t)ns[4 + r] * DIM_OUT + ti * 16 + l16, acc[ti][1][r]);
            }
    }
}

extern "C" void kernel_launch(void* const* d_in, const int* in_sizes, int n_in,
                              void* d_out, int out_size, void* d_ws, size_t ws_size,
                              hipStream_t stream) {
    const float* x  = (const float*)d_in[0];
    const int*   ei = (const int*)d_in[1];
    const float* W0 = (const float*)d_in[2];
    const float* b0 = (const float*)d_in[3];
    const float* W1 = (const float*)d_in[4];
    const float* b1 = (const float*)d_in[5];
    const float* W2 = (const float*)d_in[6];
    const float* b2 = (const float*)d_in[7];
    float* out = (float*)d_out;

    unsigned short* wt = (unsigned short*)d_ws;
    const size_t WT_BYTES = (size_t)320 * PAD * sizeof(unsigned short);  // 87040 (256-aligned)
    unsigned short* xbf = (unsigned short*)((char*)d_ws + WT_BYTES);
    const size_t need = WT_BYTES + (size_t)N_NODES * DIM_IN * sizeof(unsigned short); // ~6.5 MB

    if (ws_size >= need) {
        // fused: zero out + x->bf16 table + weight tables, one dispatch
        prep_all<<<(N_NODES * DIM_IN / 4 + 255) / 256, 256, 0, stream>>>(
            x, W0, W1, W2, wt, xbf, (float4*)out);
        edge_mlp_mfma<true><<<N_EDGES / 128, 256, 0, stream>>>(
            x, xbf, ei, wt, b0, b1, b2, out);
    } else {
        // fallback: 3-dispatch path, f32 x gather
        hipMemsetAsync(out, 0, (size_t)N_NODES * DIM_OUT * sizeof(float), stream);
        prep_weights<<<(320 * PAD + 255) / 256, 256, 0, stream>>>(W0, W1, W2, wt);
        edge_mlp_mfma<false><<<N_EDGES / 128, 256, 0, stream>>>(
            x, nullptr, ei, wt, b0, b1, b2, out);
    }
}